// Round 5
// baseline (216.169 us; speedup 1.0000x reference)
//
#include <hip/hip_runtime.h>
#include <hip/hip_fp16.h>

#define N_NODES 100000
#define EMB     64
#define N_EDGES 1200000
#define ALPHA   0.25f
#define SCAN_CHUNK 1024
#define NPART ((N_NODES + SCAN_CHUNK - 1) / SCAN_CHUNK)   // 98

// ---------------------------------------------------------------------------
// Format detection (evidence-only flags, OR-accumulated) + cnt zeroing:
//   flags[0] != 0  ->  mask has nonzero bytes at i%4!=0  ->  1-byte bool
//   flags[1] != 0  ->  idx has nonzero odd words         ->  int32 (NOT i64)
// flags must be pre-zeroed (tiny 64B memset); cnt is only plain-stored here.
// ---------------------------------------------------------------------------
__global__ void k_detect(const unsigned char* __restrict__ maskB,
                         const int* __restrict__ idx, int* __restrict__ flags,
                         int* __restrict__ cnt) {
    int tid = blockIdx.x * blockDim.x + threadIdx.x;    // 64 x 256 = 16384
    int lane = threadIdx.x & 63;
    bool mev = (tid & 3) && maskB[tid];
    if (__any(mev) && lane == 0) atomicOr(&flags[0], 1);
    bool iev = (tid < 4096) && (idx[2 * tid + 1] != 0);
    if (__any(iev) && lane == 0) atomicOr(&flags[1], 1);
    for (int i = tid; i < N_NODES; i += 64 * 256) cnt[i] = 0;
}

__device__ __forceinline__ int idx_row(const int* idx, int i64, int e) {
    return i64 ? idx[2 * e] : idx[e];
}
__device__ __forceinline__ int idx_col(const int* idx, int i64, int e) {
    return i64 ? idx[2 * (N_EDGES + e)] : idx[N_EDGES + e];
}
__device__ __forceinline__ int edge_mask(const void* maskp, int mbool, int e) {
    return mbool ? (int)((const unsigned char*)maskp)[e] : ((const int*)maskp)[e];
}

// Count-only histogram: one non-returning int atomic per active edge.
// (rank array removed — slot allocation moved to k_fill's cursor atomic.)
__global__ void k_hist(const float* __restrict__ ea, const void* maskp,
                       const int* __restrict__ idx, const int* __restrict__ flags,
                       int* __restrict__ cnt) {
    int e = blockIdx.x * blockDim.x + threadIdx.x;
    if (e >= N_EDGES) return;
    int mbool = flags[0] != 0, i64 = (flags[1] == 0);
    if (!edge_mask(maskp, mbool, e)) return;
    float wv = ea[e];
    if (wv == 0.0f) return;
    int c = idx_col(idx, i64, e);
    if ((unsigned)c >= N_NODES) return;
    atomicAdd(&cnt[c], 1);
}

// Single-kernel scan: slices disjoint, base claimed via one atomicAdd on
// gTotal. Writes row_start AND cursor (fill's allocation cursors).
__global__ void k_scanx(const int* __restrict__ cnt, int* __restrict__ gTotal,
                        int* __restrict__ row_start, int* __restrict__ cursor) {
    __shared__ int sh[256];
    __shared__ int sbase;
    int tid = threadIdx.x;
    int base = blockIdx.x * SCAN_CHUNK + tid * 4;
    int v[4];
    int s = 0;
#pragma unroll
    for (int k = 0; k < 4; ++k) {
        int i = base + k;
        v[k] = (i < N_NODES) ? cnt[i] : 0;
        s += v[k];
    }
    sh[tid] = s;
    __syncthreads();
    for (int d = 1; d < 256; d <<= 1) {
        int t = (tid >= d) ? sh[tid - d] : 0;
        __syncthreads();
        sh[tid] += t;
        __syncthreads();
    }
    if (tid == 255) sbase = atomicAdd(gTotal, sh[255]);
    __syncthreads();
    int off = sbase + sh[tid] - s;                 // exclusive within block
#pragma unroll
    for (int k = 0; k < 4; ++k) {
        int i = base + k;
        if (i < N_NODES) { row_start[i] = off; cursor[i] = off; off += v[k]; }
    }
}

// Fill CSR: slot allocated by cursor atomic (returns position), storing the
// RAW weight w (normalization folded into the scaled-t gather formulation).
__global__ void k_fill(const float* __restrict__ ea, const void* maskp,
                       const int* __restrict__ idx, const int* __restrict__ flags,
                       int* __restrict__ cursor, int2* __restrict__ csr) {
    int e = blockIdx.x * blockDim.x + threadIdx.x;
    if (e >= N_EDGES) return;
    int mbool = flags[0] != 0, i64 = (flags[1] == 0);
    if (!edge_mask(maskp, mbool, e)) return;
    float wv = ea[e];
    if (wv == 0.0f) return;
    int c = idx_col(idx, i64, e);
    if ((unsigned)c >= N_NODES) return;
    int r = idx_row(idx, i64, e);
    int rok = (unsigned)r < N_NODES;
    int p = atomicAdd(&cursor[c], 1);
    if ((unsigned)p < N_EDGES)
        csr[p] = make_int2(__float_as_int(rok ? wv : 0.0f), rok ? r : 0);
}

__device__ __forceinline__ void slice_bounds(const int* row_start, const int* cnt,
                                             int n, int& beg, int& end) {
    beg = row_start[n];
    if (beg < 0) beg = 0;
    if (beg > N_EDGES) beg = N_EDGES;
    int c = cnt[n];
    if (c < 0) c = 0;
    end = beg + c;
    if (end > N_EDGES) end = N_EDGES;
}

// Fused deg + dinv/sd + x->t0 conversion. 8 lanes/node:
//   deg[n] = sum of raw w over the node's CSR slice (8-lane strided + shuffle
//   reduce, NO atomics), dinv = rsqrt(deg), sd = sqrt(deg),
//   t0[n] = fp16(dinv[n] * x[n])  (scaled-intermediate form).
__global__ __launch_bounds__(256) void k_degconv(
        const int* __restrict__ row_start, const int* __restrict__ cnt,
        const int2* __restrict__ csr, const float4* __restrict__ x4,
        float4* __restrict__ t0, float* __restrict__ dinv, float* __restrict__ sd) {
    int t = blockIdx.x * blockDim.x + threadIdx.x;
    int n = t >> 3;
    int q = t & 7;
    if (n >= N_NODES) return;
    int beg, end;
    slice_bounds(row_start, cnt, n, beg, end);
    float s = 0.0f;
    for (int j = beg + q; j < end; j += 8) s += __int_as_float(csr[j].x);
    s += __shfl_xor(s, 1);
    s += __shfl_xor(s, 2);
    s += __shfl_xor(s, 4);
    float di = (s > 0.0f) ? rsqrtf(s) : 0.0f;
    if (q == 0) {
        dinv[n] = di;
        sd[n] = (s > 0.0f) ? sqrtf(s) : 0.0f;
    }
    size_t xb = (size_t)n * 16 + q * 2;
    float4 v0 = x4[xb], v1 = x4[xb + 1];
    float4 o;
    __half2* op = reinterpret_cast<__half2*>(&o);
    op[0] = __floats2half2_rn(di * v0.x, di * v0.y);
    op[1] = __floats2half2_rn(di * v0.z, di * v0.w);
    op[2] = __floats2half2_rn(di * v1.x, di * v1.y);
    op[3] = __floats2half2_rn(di * v1.z, di * v1.w);
    t0[(size_t)n * 8 + q] = o;
}

// fp16 row accumulate: raw = 8 halves (one 16B chunk), accumulated into
// 8 f32 partials (sa = dims 0..3 of the lane's 8-dim slice, sb = dims 4..7).
__device__ __forceinline__ void accum_h8(float4& sa, float4& sb, float w,
                                         float4 raw) {
    const __half2* hp = reinterpret_cast<const __half2*>(&raw);
    float2 f0 = __half22float2(hp[0]);
    float2 f1 = __half22float2(hp[1]);
    float2 f2 = __half22float2(hp[2]);
    float2 f3 = __half22float2(hp[3]);
    sa.x += w * f0.x; sa.y += w * f0.y; sa.z += w * f1.x; sa.w += w * f1.y;
    sb.x += w * f2.x; sb.y += w * f2.y; sb.z += w * f3.x; sb.w += w * f3.y;
}

// Aggregation core, fp16 source: 8 lanes per node (row = 64 halves = 8x16B),
// fully masked x8 edge batches (8 row loads in flight for latency hiding);
// masked lanes redirect to row 0 (L1-hot) with w=0. Weights in CSR are RAW;
// caller applies the dinv scaling.
__device__ __forceinline__ void gather_core_f16(
        const int* __restrict__ row_start, const int* __restrict__ cnt,
        const int2* __restrict__ csr, const float4* __restrict__ h16,
        int n, int q, float4& sa, float4& sb) {
    int beg, end;
    slice_bounds(row_start, cnt, n, beg, end);
    sa = make_float4(0.f, 0.f, 0.f, 0.f);
    sb = make_float4(0.f, 0.f, 0.f, 0.f);
    for (int j = beg; j < end; j += 8) {
        int last = end - 1;
        int2 p[8];
#pragma unroll
        for (int k = 0; k < 8; ++k) {
            int jk = (j + k < last) ? j + k : last;
            p[k] = csr[jk];
        }
        float w[8];
        int   r[8];
#pragma unroll
        for (int k = 0; k < 8; ++k) {
            bool ak = (j + k) < end;
            w[k] = ak ? __int_as_float(p[k].x) : 0.0f;
            r[k] = ak ? min((unsigned)p[k].y, (unsigned)(N_NODES - 1)) : 0;
        }
        float4 v[8];
#pragma unroll
        for (int k = 0; k < 8; ++k) v[k] = h16[(size_t)r[k] * 8 + q];
#pragma unroll
        for (int k = 0; k < 8; ++k) accum_h8(sa, sb, w[k], v[k]);
    }
}

// Mid layer (scaled form): t_{l+1}[n] = fp16( dinv[n]^2 * sum_j w_j * t_l[r_j] ).
__global__ __launch_bounds__(256) void k_gather_mid(
        const int* __restrict__ row_start, const int* __restrict__ cnt,
        const int2* __restrict__ csr, const float* __restrict__ dinv,
        const float4* __restrict__ tsrc, float4* __restrict__ tdst) {
    int t = blockIdx.x * blockDim.x + threadIdx.x;
    int n = t >> 3;
    int q = t & 7;
    if (n >= N_NODES) return;
    float4 sa, sb;
    gather_core_f16(row_start, cnt, csr, tsrc, n, q, sa, sb);
    float di = dinv[n];
    float d2 = di * di;
    float4 o;
    __half2* op = reinterpret_cast<__half2*>(&o);
    op[0] = __floats2half2_rn(d2 * sa.x, d2 * sa.y);
    op[1] = __floats2half2_rn(d2 * sa.z, d2 * sa.w);
    op[2] = __floats2half2_rn(d2 * sb.x, d2 * sb.y);
    op[3] = __floats2half2_rn(d2 * sb.z, d2 * sb.w);
    tdst[(size_t)n * 8 + q] = o;
}

// Last layer: h3 = dinv[n] * sum w * t2[r];  h1 = sd*t1, h2 = sd*t2;
// out = ALPHA * (x + h1 + h2 + h3), assembled in f32.
__global__ __launch_bounds__(256) void k_gather_last(
        const int* __restrict__ row_start, const int* __restrict__ cnt,
        const int2* __restrict__ csr, const float* __restrict__ dinv,
        const float* __restrict__ sd,
        const float4* __restrict__ x4, const float4* __restrict__ t1_16,
        const float4* __restrict__ t2_16, float4* __restrict__ out4) {
    int t = blockIdx.x * blockDim.x + threadIdx.x;
    int n = t >> 3;
    int q = t & 7;
    if (n >= N_NODES) return;
    float4 sa, sb;
    gather_core_f16(row_start, cnt, csr, t2_16, n, q, sa, sb);
    float di = dinv[n];
    float sdv = sd[n];
    size_t o8 = (size_t)n * 8 + q;
    float4 r1 = t1_16[o8];
    float4 r2 = t2_16[o8];
    const __half2* a1 = reinterpret_cast<const __half2*>(&r1);
    const __half2* a2 = reinterpret_cast<const __half2*>(&r2);
    float2 b10 = __half22float2(a1[0]), b11 = __half22float2(a1[1]);
    float2 b12 = __half22float2(a1[2]), b13 = __half22float2(a1[3]);
    float2 b20 = __half22float2(a2[0]), b21 = __half22float2(a2[1]);
    float2 b22 = __half22float2(a2[2]), b23 = __half22float2(a2[3]);
    size_t ox = (size_t)n * 16 + 2 * q;
    float4 x0 = x4[ox], x1 = x4[ox + 1];
    float4 o0, o1;
    o0.x = ALPHA * (x0.x + sdv * (b10.x + b20.x) + di * sa.x);
    o0.y = ALPHA * (x0.y + sdv * (b10.y + b20.y) + di * sa.y);
    o0.z = ALPHA * (x0.z + sdv * (b11.x + b21.x) + di * sa.z);
    o0.w = ALPHA * (x0.w + sdv * (b11.y + b21.y) + di * sa.w);
    o1.x = ALPHA * (x1.x + sdv * (b12.x + b22.x) + di * sb.x);
    o1.y = ALPHA * (x1.y + sdv * (b12.y + b22.y) + di * sb.y);
    o1.z = ALPHA * (x1.z + sdv * (b13.x + b23.x) + di * sb.z);
    o1.w = ALPHA * (x1.w + sdv * (b13.y + b23.y) + di * sb.w);
    out4[ox] = o0;
    out4[ox + 1] = o1;
}

extern "C" void kernel_launch(void* const* d_in, const int* in_sizes, int n_in,
                              void* d_out, int out_size, void* d_ws, size_t ws_size,
                              hipStream_t stream) {
    const float* x   = (const float*)d_in[0];
    const float* ea  = (const float*)d_in[1];
    const int*   idx = (const int*)d_in[2];
    const void*  msk = d_in[3];
    float*       out = (float*)d_out;

    char* ws = (char*)d_ws;
    size_t off = 0;
    auto alloc = [&](size_t bytes) -> void* {
        void* p = ws + off;
        off = (off + bytes + 255) & ~(size_t)255;
        return p;
    };
    int*    flags     = (int*)   alloc(64);   // flags[0..1] + gTotal at flags[8]
    int*    cnt       = (int*)   alloc(sizeof(int)   * N_NODES);
    int*    row_start = (int*)   alloc(sizeof(int)   * N_NODES);
    int*    cursor    = (int*)   alloc(sizeof(int)   * N_NODES);
    float*  dinv      = (float*) alloc(sizeof(float) * N_NODES);
    float*  sd        = (float*) alloc(sizeof(float) * N_NODES);
    int2*   csr       = (int2*)  alloc(sizeof(int2)  * N_EDGES);
    float4* t0        = (float4*)alloc(sizeof(unsigned short) * (size_t)N_NODES * EMB);
    float4* tA        = (float4*)alloc(sizeof(unsigned short) * (size_t)N_NODES * EMB);
    float4* tB        = (float4*)alloc(sizeof(unsigned short) * (size_t)N_NODES * EMB);
    int*    gTotal    = flags + 8;

    const int B = 256;
    const int gE = (N_EDGES + B - 1) / B;
    const int gG = (N_NODES * 8 + B - 1) / B;   // 3125: 8 lanes/node

    (void)hipMemsetAsync(flags, 0, 64, stream);   // flags + gTotal only
    k_detect <<<64, 256, 0, stream>>>((const unsigned char*)msk, idx, flags, cnt);
    k_hist   <<<gE, B, 0, stream>>>(ea, msk, idx, flags, cnt);
    k_scanx  <<<NPART, 256, 0, stream>>>(cnt, gTotal, row_start, cursor);
    k_fill   <<<gE, B, 0, stream>>>(ea, msk, idx, flags, cursor, csr);
    k_degconv<<<gG, B, 0, stream>>>(row_start, cnt, csr, (const float4*)x,
                                    t0, dinv, sd);

    k_gather_mid <<<gG, B, 0, stream>>>(row_start, cnt, csr, dinv, t0, tA);
    k_gather_mid <<<gG, B, 0, stream>>>(row_start, cnt, csr, dinv, tA, tB);
    k_gather_last<<<gG, B, 0, stream>>>(row_start, cnt, csr, dinv, sd,
                                        (const float4*)x, tA, tB, (float4*)out);
}

// Round 6
// 213.566 us; speedup vs baseline: 1.0122x; 1.0122x over previous
//
#include <hip/hip_runtime.h>
#include <hip/hip_fp16.h>

#define N_NODES 100000
#define EMB     64
#define N_EDGES 1200000
#define ALPHA   0.25f
#define SCAN_CHUNK 1024
#define NPART ((N_NODES + SCAN_CHUNK - 1) / SCAN_CHUNK)   // 98

// ---------------------------------------------------------------------------
// Format detection (evidence-only flags, OR-accumulated) + cnt zeroing:
//   flags[0] != 0  ->  mask has nonzero bytes at i%4!=0  ->  1-byte bool
//   flags[1] != 0  ->  idx has nonzero odd words         ->  int32 (NOT i64)
// flags must be pre-zeroed (tiny 64B memset); cnt is only plain-stored here.
// ---------------------------------------------------------------------------
__global__ void k_detect(const unsigned char* __restrict__ maskB,
                         const int* __restrict__ idx, int* __restrict__ flags,
                         int* __restrict__ cnt) {
    int tid = blockIdx.x * blockDim.x + threadIdx.x;    // 64 x 256 = 16384
    int lane = threadIdx.x & 63;
    bool mev = (tid & 3) && maskB[tid];
    if (__any(mev) && lane == 0) atomicOr(&flags[0], 1);
    bool iev = (tid < 4096) && (idx[2 * tid + 1] != 0);
    if (__any(iev) && lane == 0) atomicOr(&flags[1], 1);
    for (int i = tid; i < N_NODES; i += 64 * 256) cnt[i] = 0;
}

__device__ __forceinline__ int idx_row(const int* idx, int i64, int e) {
    return i64 ? idx[2 * e] : idx[e];
}
__device__ __forceinline__ int idx_col(const int* idx, int i64, int e) {
    return i64 ? idx[2 * (N_EDGES + e)] : idx[N_EDGES + e];
}
__device__ __forceinline__ int edge_mask(const void* maskp, int mbool, int e) {
    return mbool ? (int)((const unsigned char*)maskp)[e] : ((const int*)maskp)[e];
}

// Count-only histogram: one non-returning int atomic per active edge.
__global__ void k_hist(const float* __restrict__ ea, const void* maskp,
                       const int* __restrict__ idx, const int* __restrict__ flags,
                       int* __restrict__ cnt) {
    int e = blockIdx.x * blockDim.x + threadIdx.x;
    if (e >= N_EDGES) return;
    int mbool = flags[0] != 0, i64 = (flags[1] == 0);
    if (!edge_mask(maskp, mbool, e)) return;
    float wv = ea[e];
    if (wv == 0.0f) return;
    int c = idx_col(idx, i64, e);
    if ((unsigned)c >= N_NODES) return;
    atomicAdd(&cnt[c], 1);
}

// Single-kernel scan: slices disjoint, base claimed via one atomicAdd on
// gTotal. Writes row_start AND cursor (fill's allocation cursors).
__global__ void k_scanx(const int* __restrict__ cnt, int* __restrict__ gTotal,
                        int* __restrict__ row_start, int* __restrict__ cursor) {
    __shared__ int sh[256];
    __shared__ int sbase;
    int tid = threadIdx.x;
    int base = blockIdx.x * SCAN_CHUNK + tid * 4;
    int v[4];
    int s = 0;
#pragma unroll
    for (int k = 0; k < 4; ++k) {
        int i = base + k;
        v[k] = (i < N_NODES) ? cnt[i] : 0;
        s += v[k];
    }
    sh[tid] = s;
    __syncthreads();
    for (int d = 1; d < 256; d <<= 1) {
        int t = (tid >= d) ? sh[tid - d] : 0;
        __syncthreads();
        sh[tid] += t;
        __syncthreads();
    }
    if (tid == 255) sbase = atomicAdd(gTotal, sh[255]);
    __syncthreads();
    int off = sbase + sh[tid] - s;                 // exclusive within block
#pragma unroll
    for (int k = 0; k < 4; ++k) {
        int i = base + k;
        if (i < N_NODES) { row_start[i] = off; cursor[i] = off; off += v[k]; }
    }
}

// Fill CSR: slot allocated by cursor atomic (returns position), storing the
// RAW weight w (normalization folded into the scaled-t gather formulation).
__global__ void k_fill(const float* __restrict__ ea, const void* maskp,
                       const int* __restrict__ idx, const int* __restrict__ flags,
                       int* __restrict__ cursor, int2* __restrict__ csr) {
    int e = blockIdx.x * blockDim.x + threadIdx.x;
    if (e >= N_EDGES) return;
    int mbool = flags[0] != 0, i64 = (flags[1] == 0);
    if (!edge_mask(maskp, mbool, e)) return;
    float wv = ea[e];
    if (wv == 0.0f) return;
    int c = idx_col(idx, i64, e);
    if ((unsigned)c >= N_NODES) return;
    int r = idx_row(idx, i64, e);
    int rok = (unsigned)r < N_NODES;
    int p = atomicAdd(&cursor[c], 1);
    if ((unsigned)p < N_EDGES)
        csr[p] = make_int2(__float_as_int(rok ? wv : 0.0f), rok ? r : 0);
}

__device__ __forceinline__ void slice_bounds(const int* row_start, const int* cnt,
                                             int n, int& beg, int& end) {
    beg = row_start[n];
    if (beg < 0) beg = 0;
    if (beg > N_EDGES) beg = N_EDGES;
    int c = cnt[n];
    if (c < 0) c = 0;
    end = beg + c;
    if (end > N_EDGES) end = N_EDGES;
}

// Fused deg + dinv/sd + x->t0 conversion. 8 lanes/node:
//   deg[n] = sum of raw w over the node's CSR slice (8-lane strided + shuffle
//   reduce, NO atomics), dinv = rsqrt(deg), sd = sqrt(deg),
//   t0[n] = fp16(dinv[n] * x[n])  (scaled-intermediate form).
__global__ __launch_bounds__(256) void k_degconv(
        const int* __restrict__ row_start, const int* __restrict__ cnt,
        const int2* __restrict__ csr, const float4* __restrict__ x4,
        float4* __restrict__ t0, float* __restrict__ dinv, float* __restrict__ sd) {
    int t = blockIdx.x * blockDim.x + threadIdx.x;
    int n = t >> 3;
    int q = t & 7;
    if (n >= N_NODES) return;
    int beg, end;
    slice_bounds(row_start, cnt, n, beg, end);
    float s = 0.0f;
    for (int j = beg + q; j < end; j += 8) s += __int_as_float(csr[j].x);
    s += __shfl_xor(s, 1);
    s += __shfl_xor(s, 2);
    s += __shfl_xor(s, 4);
    float di = (s > 0.0f) ? rsqrtf(s) : 0.0f;
    if (q == 0) {
        dinv[n] = di;
        sd[n] = (s > 0.0f) ? sqrtf(s) : 0.0f;
    }
    size_t xb = (size_t)n * 16 + q * 2;
    float4 v0 = x4[xb], v1 = x4[xb + 1];
    float4 o;
    __half2* op = reinterpret_cast<__half2*>(&o);
    op[0] = __floats2half2_rn(di * v0.x, di * v0.y);
    op[1] = __floats2half2_rn(di * v0.z, di * v0.w);
    op[2] = __floats2half2_rn(di * v1.x, di * v1.y);
    op[3] = __floats2half2_rn(di * v1.z, di * v1.w);
    t0[(size_t)n * 8 + q] = o;
}

// fp16 row accumulate: raw = 8 halves (one 16B chunk), accumulated into
// 8 f32 partials (sa = dims 0..3 of the lane's 8-dim slice, sb = dims 4..7).
__device__ __forceinline__ void accum_h8(float4& sa, float4& sb, float w,
                                         float4 raw) {
    const __half2* hp = reinterpret_cast<const __half2*>(&raw);
    float2 f0 = __half22float2(hp[0]);
    float2 f1 = __half22float2(hp[1]);
    float2 f2 = __half22float2(hp[2]);
    float2 f3 = __half22float2(hp[3]);
    sa.x += w * f0.x; sa.y += w * f0.y; sa.z += w * f1.x; sa.w += w * f1.y;
    sb.x += w * f2.x; sb.y += w * f2.y; sb.z += w * f3.x; sb.w += w * f3.y;
}

// Aggregation core, fp16 source: 8 lanes per node (row = 64 halves = 8x16B),
// fully masked x4 edge batches (Round-4 known-good VGPR footprint);
// masked lanes redirect to row 0 (L1-hot) with w=0. Weights in CSR are RAW;
// caller applies the dinv scaling.
__device__ __forceinline__ void gather_core_f16(
        const int* __restrict__ row_start, const int* __restrict__ cnt,
        const int2* __restrict__ csr, const float4* __restrict__ h16,
        int n, int q, float4& sa, float4& sb) {
    int beg, end;
    slice_bounds(row_start, cnt, n, beg, end);
    sa = make_float4(0.f, 0.f, 0.f, 0.f);
    sb = make_float4(0.f, 0.f, 0.f, 0.f);
    for (int j = beg; j < end; j += 4) {
        int last = end - 1;
        int j1 = j + 1 < last ? j + 1 : last;
        int j2 = j + 2 < last ? j + 2 : last;
        int j3 = j + 3 < last ? j + 3 : last;
        int2 p0 = csr[j];
        int2 p1 = csr[j1];
        int2 p2 = csr[j2];
        int2 p3 = csr[j3];
        bool a1 = j + 1 < end, a2 = j + 2 < end, a3 = j + 3 < end;
        float w0 = __int_as_float(p0.x);
        float w1 = a1 ? __int_as_float(p1.x) : 0.0f;
        float w2 = a2 ? __int_as_float(p2.x) : 0.0f;
        float w3 = a3 ? __int_as_float(p3.x) : 0.0f;
        int r0 = min((unsigned)p0.y, (unsigned)(N_NODES - 1));
        int r1 = a1 ? min((unsigned)p1.y, (unsigned)(N_NODES - 1)) : 0;
        int r2 = a2 ? min((unsigned)p2.y, (unsigned)(N_NODES - 1)) : 0;
        int r3 = a3 ? min((unsigned)p3.y, (unsigned)(N_NODES - 1)) : 0;
        float4 v0 = h16[(size_t)r0 * 8 + q];
        float4 v1 = h16[(size_t)r1 * 8 + q];
        float4 v2 = h16[(size_t)r2 * 8 + q];
        float4 v3 = h16[(size_t)r3 * 8 + q];
        accum_h8(sa, sb, w0, v0);
        accum_h8(sa, sb, w1, v1);
        accum_h8(sa, sb, w2, v2);
        accum_h8(sa, sb, w3, v3);
    }
}

// Mid layer (scaled form): t_{l+1}[n] = fp16( dinv[n]^2 * sum_j w_j * t_l[r_j] ).
__global__ __launch_bounds__(256) void k_gather_mid(
        const int* __restrict__ row_start, const int* __restrict__ cnt,
        const int2* __restrict__ csr, const float* __restrict__ dinv,
        const float4* __restrict__ tsrc, float4* __restrict__ tdst) {
    int t = blockIdx.x * blockDim.x + threadIdx.x;
    int n = t >> 3;
    int q = t & 7;
    if (n >= N_NODES) return;
    float4 sa, sb;
    gather_core_f16(row_start, cnt, csr, tsrc, n, q, sa, sb);
    float di = dinv[n];
    float d2 = di * di;
    float4 o;
    __half2* op = reinterpret_cast<__half2*>(&o);
    op[0] = __floats2half2_rn(d2 * sa.x, d2 * sa.y);
    op[1] = __floats2half2_rn(d2 * sa.z, d2 * sa.w);
    op[2] = __floats2half2_rn(d2 * sb.x, d2 * sb.y);
    op[3] = __floats2half2_rn(d2 * sb.z, d2 * sb.w);
    tdst[(size_t)n * 8 + q] = o;
}

// Last layer: h3 = dinv[n] * sum w * t2[r];  h1 = sd*t1, h2 = sd*t2;
// out = ALPHA * (x + h1 + h2 + h3), assembled in f32.
__global__ __launch_bounds__(256) void k_gather_last(
        const int* __restrict__ row_start, const int* __restrict__ cnt,
        const int2* __restrict__ csr, const float* __restrict__ dinv,
        const float* __restrict__ sd,
        const float4* __restrict__ x4, const float4* __restrict__ t1_16,
        const float4* __restrict__ t2_16, float4* __restrict__ out4) {
    int t = blockIdx.x * blockDim.x + threadIdx.x;
    int n = t >> 3;
    int q = t & 7;
    if (n >= N_NODES) return;
    float4 sa, sb;
    gather_core_f16(row_start, cnt, csr, t2_16, n, q, sa, sb);
    float di = dinv[n];
    float sdv = sd[n];
    size_t o8 = (size_t)n * 8 + q;
    float4 r1 = t1_16[o8];
    float4 r2 = t2_16[o8];
    const __half2* a1 = reinterpret_cast<const __half2*>(&r1);
    const __half2* a2 = reinterpret_cast<const __half2*>(&r2);
    float2 b10 = __half22float2(a1[0]), b11 = __half22float2(a1[1]);
    float2 b12 = __half22float2(a1[2]), b13 = __half22float2(a1[3]);
    float2 b20 = __half22float2(a2[0]), b21 = __half22float2(a2[1]);
    float2 b22 = __half22float2(a2[2]), b23 = __half22float2(a2[3]);
    size_t ox = (size_t)n * 16 + 2 * q;
    float4 x0 = x4[ox], x1 = x4[ox + 1];
    float4 o0, o1;
    o0.x = ALPHA * (x0.x + sdv * (b10.x + b20.x) + di * sa.x);
    o0.y = ALPHA * (x0.y + sdv * (b10.y + b20.y) + di * sa.y);
    o0.z = ALPHA * (x0.z + sdv * (b11.x + b21.x) + di * sa.z);
    o0.w = ALPHA * (x0.w + sdv * (b11.y + b21.y) + di * sa.w);
    o1.x = ALPHA * (x1.x + sdv * (b12.x + b22.x) + di * sb.x);
    o1.y = ALPHA * (x1.y + sdv * (b12.y + b22.y) + di * sb.y);
    o1.z = ALPHA * (x1.z + sdv * (b13.x + b23.x) + di * sb.z);
    o1.w = ALPHA * (x1.w + sdv * (b13.y + b23.y) + di * sb.w);
    out4[ox] = o0;
    out4[ox + 1] = o1;
}

extern "C" void kernel_launch(void* const* d_in, const int* in_sizes, int n_in,
                              void* d_out, int out_size, void* d_ws, size_t ws_size,
                              hipStream_t stream) {
    const float* x   = (const float*)d_in[0];
    const float* ea  = (const float*)d_in[1];
    const int*   idx = (const int*)d_in[2];
    const void*  msk = d_in[3];
    float*       out = (float*)d_out;

    char* ws = (char*)d_ws;
    size_t off = 0;
    auto alloc = [&](size_t bytes) -> void* {
        void* p = ws + off;
        off = (off + bytes + 255) & ~(size_t)255;
        return p;
    };
    int*    flags     = (int*)   alloc(64);   // flags[0..1] + gTotal at flags[8]
    int*    cnt       = (int*)   alloc(sizeof(int)   * N_NODES);
    int*    row_start = (int*)   alloc(sizeof(int)   * N_NODES);
    int*    cursor    = (int*)   alloc(sizeof(int)   * N_NODES);
    float*  dinv      = (float*) alloc(sizeof(float) * N_NODES);
    float*  sd        = (float*) alloc(sizeof(float) * N_NODES);
    int2*   csr       = (int2*)  alloc(sizeof(int2)  * N_EDGES);
    float4* t0        = (float4*)alloc(sizeof(unsigned short) * (size_t)N_NODES * EMB);
    float4* tA        = (float4*)alloc(sizeof(unsigned short) * (size_t)N_NODES * EMB);
    float4* tB        = (float4*)alloc(sizeof(unsigned short) * (size_t)N_NODES * EMB);
    int*    gTotal    = flags + 8;

    const int B = 256;
    const int gE = (N_EDGES + B - 1) / B;
    const int gG = (N_NODES * 8 + B - 1) / B;   // 3125: 8 lanes/node

    (void)hipMemsetAsync(flags, 0, 64, stream);   // flags + gTotal only
    k_detect <<<64, 256, 0, stream>>>((const unsigned char*)msk, idx, flags, cnt);
    k_hist   <<<gE, B, 0, stream>>>(ea, msk, idx, flags, cnt);
    k_scanx  <<<NPART, 256, 0, stream>>>(cnt, gTotal, row_start, cursor);
    k_fill   <<<gE, B, 0, stream>>>(ea, msk, idx, flags, cursor, csr);
    k_degconv<<<gG, B, 0, stream>>>(row_start, cnt, csr, (const float4*)x,
                                    t0, dinv, sd);

    k_gather_mid <<<gG, B, 0, stream>>>(row_start, cnt, csr, dinv, t0, tA);
    k_gather_mid <<<gG, B, 0, stream>>>(row_start, cnt, csr, dinv, tA, tB);
    k_gather_last<<<gG, B, 0, stream>>>(row_start, cnt, csr, dinv, sd,
                                        (const float4*)x, tA, tB, (float4*)out);
}

// Round 7
// 190.453 us; speedup vs baseline: 1.1350x; 1.1214x over previous
//
#include <hip/hip_runtime.h>
#include <hip/hip_fp16.h>

#define N_NODES 100000
#define EMB     64
#define N_EDGES 1200000
#define ALPHA   0.25f
#define SCAN_CHUNK 1024
#define NPART ((N_NODES + SCAN_CHUNK - 1) / SCAN_CHUNK)   // 98

// ---------------------------------------------------------------------------
// Format detection — evidence-only flags, OR-accumulated:
//   flags[0] != 0  ->  mask has nonzero bytes at i%4!=0  ->  1-byte bool
//   flags[1] != 0  ->  idx has nonzero odd words         ->  int32 (NOT i64)
// ---------------------------------------------------------------------------
__global__ void k_detect(const unsigned char* __restrict__ maskB,
                         const int* __restrict__ idx, int* __restrict__ flags) {
    int tid = blockIdx.x * blockDim.x + threadIdx.x;    // 64 x 256 = 16384
    int lane = threadIdx.x & 63;
    bool mev = (tid & 3) && maskB[tid];
    if (__any(mev) && lane == 0) atomicOr(&flags[0], 1);
    bool iev = (tid < 4096) && (idx[2 * tid + 1] != 0);
    if (__any(iev) && lane == 0) atomicOr(&flags[1], 1);
}

__device__ __forceinline__ int idx_row(const int* idx, int i64, int e) {
    return i64 ? idx[2 * e] : idx[e];
}
__device__ __forceinline__ int idx_col(const int* idx, int i64, int e) {
    return i64 ? idx[2 * (N_EDGES + e)] : idx[N_EDGES + e];
}
__device__ __forceinline__ int edge_mask(const void* maskp, int mbool, int e) {
    return mbool ? (int)((const unsigned char*)maskp)[e] : ((const int*)maskp)[e];
}

// ONE returning int atomic per active edge (rank within its node). The
// returning atomic lives HERE (lightweight kernel) — R6 measured that putting
// it in the scatter-store fill kernel costs ~18 us extra.
__global__ void k_hist(const float* __restrict__ ea, const void* maskp,
                       const int* __restrict__ idx, const int* __restrict__ flags,
                       int* __restrict__ cnt, int* __restrict__ rank) {
    int e = blockIdx.x * blockDim.x + threadIdx.x;
    if (e >= N_EDGES) return;
    int mbool = flags[0] != 0, i64 = (flags[1] == 0);
    if (!edge_mask(maskp, mbool, e)) return;
    float wv = ea[e];
    if (wv == 0.0f) return;
    int c = idx_col(idx, i64, e);
    if ((unsigned)c >= N_NODES) return;
    rank[e] = atomicAdd(&cnt[c], 1);
}

// Single-kernel scan: slices disjoint, base claimed via one atomicAdd on gTotal.
__global__ void k_scanx(const int* __restrict__ cnt, int* __restrict__ gTotal,
                        int* __restrict__ row_start) {
    __shared__ int sh[256];
    __shared__ int sbase;
    int tid = threadIdx.x;
    int base = blockIdx.x * SCAN_CHUNK + tid * 4;
    int v[4];
    int s = 0;
#pragma unroll
    for (int k = 0; k < 4; ++k) {
        int i = base + k;
        v[k] = (i < N_NODES) ? cnt[i] : 0;
        s += v[k];
    }
    sh[tid] = s;
    __syncthreads();
    for (int d = 1; d < 256; d <<= 1) {
        int t = (tid >= d) ? sh[tid - d] : 0;
        __syncthreads();
        sh[tid] += t;
        __syncthreads();
    }
    if (tid == 255) sbase = atomicAdd(gTotal, sh[255]);
    __syncthreads();
    int off = sbase + sh[tid] - s;                 // exclusive within block
#pragma unroll
    for (int k = 0; k < 4; ++k) {
        int i = base + k;
        if (i < N_NODES) { row_start[i] = off; off += v[k]; }
    }
}

// Fill CSR — atomic-free: slot p = row_start[col] + rank[e], storing the RAW
// weight w (normalization folded into the scaled-t gather formulation).
__global__ void k_fill(const float* __restrict__ ea, const void* maskp,
                       const int* __restrict__ idx, const int* __restrict__ flags,
                       const int* __restrict__ row_start, const int* __restrict__ rank,
                       int2* __restrict__ csr) {
    int e = blockIdx.x * blockDim.x + threadIdx.x;
    if (e >= N_EDGES) return;
    int mbool = flags[0] != 0, i64 = (flags[1] == 0);
    if (!edge_mask(maskp, mbool, e)) return;
    float wv = ea[e];
    if (wv == 0.0f) return;
    int c = idx_col(idx, i64, e);
    if ((unsigned)c >= N_NODES) return;
    int r = idx_row(idx, i64, e);
    int rok = (unsigned)r < N_NODES;
    int p = row_start[c] + rank[e];
    if ((unsigned)p < N_EDGES)
        csr[p] = make_int2(__float_as_int(rok ? wv : 0.0f), rok ? r : 0);
}

__device__ __forceinline__ void slice_bounds(const int* row_start, const int* cnt,
                                             int n, int& beg, int& end) {
    beg = row_start[n];
    if (beg < 0) beg = 0;
    if (beg > N_EDGES) beg = N_EDGES;
    int c = cnt[n];
    if (c < 0) c = 0;
    end = beg + c;
    if (end > N_EDGES) end = N_EDGES;
}

// Fused deg + dinv/sd + x->t0 conversion. 8 lanes/node:
//   deg[n] = sum of raw w over the node's CSR slice (8-lane strided + shuffle
//   reduce, NO atomics), dinv = rsqrt(deg), sd = sqrt(deg),
//   t0[n] = fp16(dinv[n] * x[n])  (scaled-intermediate form).
__global__ __launch_bounds__(256) void k_degconv(
        const int* __restrict__ row_start, const int* __restrict__ cnt,
        const int2* __restrict__ csr, const float4* __restrict__ x4,
        float4* __restrict__ t0, float* __restrict__ dinv, float* __restrict__ sd) {
    int t = blockIdx.x * blockDim.x + threadIdx.x;
    int n = t >> 3;
    int q = t & 7;
    if (n >= N_NODES) return;
    int beg, end;
    slice_bounds(row_start, cnt, n, beg, end);
    float s = 0.0f;
    for (int j = beg + q; j < end; j += 8) s += __int_as_float(csr[j].x);
    s += __shfl_xor(s, 1);
    s += __shfl_xor(s, 2);
    s += __shfl_xor(s, 4);
    float di = (s > 0.0f) ? rsqrtf(s) : 0.0f;
    if (q == 0) {
        dinv[n] = di;
        sd[n] = (s > 0.0f) ? sqrtf(s) : 0.0f;
    }
    size_t xb = (size_t)n * 16 + q * 2;
    float4 v0 = x4[xb], v1 = x4[xb + 1];
    float4 o;
    __half2* op = reinterpret_cast<__half2*>(&o);
    op[0] = __floats2half2_rn(di * v0.x, di * v0.y);
    op[1] = __floats2half2_rn(di * v0.z, di * v0.w);
    op[2] = __floats2half2_rn(di * v1.x, di * v1.y);
    op[3] = __floats2half2_rn(di * v1.z, di * v1.w);
    t0[(size_t)n * 8 + q] = o;
}

// fp16 row accumulate: raw = 8 halves (one 16B chunk), accumulated into
// 8 f32 partials (sa = dims 0..3 of the lane's 8-dim slice, sb = dims 4..7).
__device__ __forceinline__ void accum_h8(float4& sa, float4& sb, float w,
                                         float4 raw) {
    const __half2* hp = reinterpret_cast<const __half2*>(&raw);
    float2 f0 = __half22float2(hp[0]);
    float2 f1 = __half22float2(hp[1]);
    float2 f2 = __half22float2(hp[2]);
    float2 f3 = __half22float2(hp[3]);
    sa.x += w * f0.x; sa.y += w * f0.y; sa.z += w * f1.x; sa.w += w * f1.y;
    sb.x += w * f2.x; sb.y += w * f2.y; sb.z += w * f3.x; sb.w += w * f3.y;
}

// Aggregation core, fp16 source: 8 lanes per node (row = 64 halves = 8x16B),
// fully masked x4 edge batches; masked lanes redirect to row 0 (L1-hot) with
// w=0. NEW: 1-batch csr software prefetch — next batch's 4 csr entries are
// loaded during this batch's row loads/FMAs, removing the csr(L2)->row(L3)
// serial hop from the steady-state critical path. +8 VGPR only.
__device__ __forceinline__ void gather_core_f16(
        const int* __restrict__ row_start, const int* __restrict__ cnt,
        const int2* __restrict__ csr, const float4* __restrict__ h16,
        int n, int q, float4& sa, float4& sb) {
    int beg, end;
    slice_bounds(row_start, cnt, n, beg, end);
    sa = make_float4(0.f, 0.f, 0.f, 0.f);
    sb = make_float4(0.f, 0.f, 0.f, 0.f);
    if (beg >= end) return;
    int last = end - 1;
    int2 c0 = csr[beg];
    int2 c1 = csr[beg + 1 < last ? beg + 1 : last];
    int2 c2 = csr[beg + 2 < last ? beg + 2 : last];
    int2 c3 = csr[beg + 3 < last ? beg + 3 : last];
    for (int j = beg; j < end; j += 4) {
        int2 p0 = c0, p1 = c1, p2 = c2, p3 = c3;
        int jn = j + 4;
        if (jn < end) {                      // prefetch next batch's csr
            c0 = csr[jn];
            c1 = csr[jn + 1 < last ? jn + 1 : last];
            c2 = csr[jn + 2 < last ? jn + 2 : last];
            c3 = csr[jn + 3 < last ? jn + 3 : last];
        }
        bool a1 = j + 1 < end, a2 = j + 2 < end, a3 = j + 3 < end;
        float w0 = __int_as_float(p0.x);
        float w1 = a1 ? __int_as_float(p1.x) : 0.0f;
        float w2 = a2 ? __int_as_float(p2.x) : 0.0f;
        float w3 = a3 ? __int_as_float(p3.x) : 0.0f;
        int r0 = min((unsigned)p0.y, (unsigned)(N_NODES - 1));
        int r1 = a1 ? min((unsigned)p1.y, (unsigned)(N_NODES - 1)) : 0;
        int r2 = a2 ? min((unsigned)p2.y, (unsigned)(N_NODES - 1)) : 0;
        int r3 = a3 ? min((unsigned)p3.y, (unsigned)(N_NODES - 1)) : 0;
        float4 v0 = h16[(size_t)r0 * 8 + q];
        float4 v1 = h16[(size_t)r1 * 8 + q];
        float4 v2 = h16[(size_t)r2 * 8 + q];
        float4 v3 = h16[(size_t)r3 * 8 + q];
        accum_h8(sa, sb, w0, v0);
        accum_h8(sa, sb, w1, v1);
        accum_h8(sa, sb, w2, v2);
        accum_h8(sa, sb, w3, v3);
    }
}

// Mid layer (scaled form): t_{l+1}[n] = fp16( dinv[n]^2 * sum_j w_j * t_l[r_j] ).
__global__ __launch_bounds__(256) void k_gather_mid(
        const int* __restrict__ row_start, const int* __restrict__ cnt,
        const int2* __restrict__ csr, const float* __restrict__ dinv,
        const float4* __restrict__ tsrc, float4* __restrict__ tdst) {
    int t = blockIdx.x * blockDim.x + threadIdx.x;
    int n = t >> 3;
    int q = t & 7;
    if (n >= N_NODES) return;
    float4 sa, sb;
    gather_core_f16(row_start, cnt, csr, tsrc, n, q, sa, sb);
    float di = dinv[n];
    float d2 = di * di;
    float4 o;
    __half2* op = reinterpret_cast<__half2*>(&o);
    op[0] = __floats2half2_rn(d2 * sa.x, d2 * sa.y);
    op[1] = __floats2half2_rn(d2 * sa.z, d2 * sa.w);
    op[2] = __floats2half2_rn(d2 * sb.x, d2 * sb.y);
    op[3] = __floats2half2_rn(d2 * sb.z, d2 * sb.w);
    tdst[(size_t)n * 8 + q] = o;
}

// Last layer: h3 = dinv[n] * sum w * t2[r];  h1 = sd*t1, h2 = sd*t2;
// out = ALPHA * (x + h1 + h2 + h3), assembled in f32.
__global__ __launch_bounds__(256) void k_gather_last(
        const int* __restrict__ row_start, const int* __restrict__ cnt,
        const int2* __restrict__ csr, const float* __restrict__ dinv,
        const float* __restrict__ sd,
        const float4* __restrict__ x4, const float4* __restrict__ t1_16,
        const float4* __restrict__ t2_16, float4* __restrict__ out4) {
    int t = blockIdx.x * blockDim.x + threadIdx.x;
    int n = t >> 3;
    int q = t & 7;
    if (n >= N_NODES) return;
    float4 sa, sb;
    gather_core_f16(row_start, cnt, csr, t2_16, n, q, sa, sb);
    float di = dinv[n];
    float sdv = sd[n];
    size_t o8 = (size_t)n * 8 + q;
    float4 r1 = t1_16[o8];
    float4 r2 = t2_16[o8];
    const __half2* a1 = reinterpret_cast<const __half2*>(&r1);
    const __half2* a2 = reinterpret_cast<const __half2*>(&r2);
    float2 b10 = __half22float2(a1[0]), b11 = __half22float2(a1[1]);
    float2 b12 = __half22float2(a1[2]), b13 = __half22float2(a1[3]);
    float2 b20 = __half22float2(a2[0]), b21 = __half22float2(a2[1]);
    float2 b22 = __half22float2(a2[2]), b23 = __half22float2(a2[3]);
    size_t ox = (size_t)n * 16 + 2 * q;
    float4 x0 = x4[ox], x1 = x4[ox + 1];
    float4 o0, o1;
    o0.x = ALPHA * (x0.x + sdv * (b10.x + b20.x) + di * sa.x);
    o0.y = ALPHA * (x0.y + sdv * (b10.y + b20.y) + di * sa.y);
    o0.z = ALPHA * (x0.z + sdv * (b11.x + b21.x) + di * sa.z);
    o0.w = ALPHA * (x0.w + sdv * (b11.y + b21.y) + di * sa.w);
    o1.x = ALPHA * (x1.x + sdv * (b12.x + b22.x) + di * sb.x);
    o1.y = ALPHA * (x1.y + sdv * (b12.y + b22.y) + di * sb.y);
    o1.z = ALPHA * (x1.z + sdv * (b13.x + b23.x) + di * sb.z);
    o1.w = ALPHA * (x1.w + sdv * (b13.y + b23.y) + di * sb.w);
    out4[ox] = o0;
    out4[ox + 1] = o1;
}

extern "C" void kernel_launch(void* const* d_in, const int* in_sizes, int n_in,
                              void* d_out, int out_size, void* d_ws, size_t ws_size,
                              hipStream_t stream) {
    const float* x   = (const float*)d_in[0];
    const float* ea  = (const float*)d_in[1];
    const int*   idx = (const int*)d_in[2];
    const void*  msk = d_in[3];
    float*       out = (float*)d_out;

    char* ws = (char*)d_ws;
    size_t off = 0;
    auto alloc = [&](size_t bytes) -> void* {
        void* p = ws + off;
        off = (off + bytes + 255) & ~(size_t)255;
        return p;
    };
    int*    flags     = (int*)   alloc(64);   // flags[0..1] + gTotal at flags[8]
    int*    cnt       = (int*)   alloc(sizeof(int)   * N_NODES);
    int*    row_start = (int*)   alloc(sizeof(int)   * N_NODES);
    float*  dinv      = (float*) alloc(sizeof(float) * N_NODES);
    float*  sd        = (float*) alloc(sizeof(float) * N_NODES);
    int*    rank      = (int*)   alloc(sizeof(int)   * N_EDGES);
    int2*   csr       = (int2*)  alloc(sizeof(int2)  * N_EDGES);
    float4* t0        = (float4*)alloc(sizeof(unsigned short) * (size_t)N_NODES * EMB);
    float4* tA        = (float4*)alloc(sizeof(unsigned short) * (size_t)N_NODES * EMB);
    float4* tB        = (float4*)alloc(sizeof(unsigned short) * (size_t)N_NODES * EMB);
    int*    gTotal    = flags + 8;

    const int B = 256;
    const int gE = (N_EDGES + B - 1) / B;
    const int gG = (N_NODES * 8 + B - 1) / B;   // 3125: 8 lanes/node

    // flags block + cnt are adjacent in ws -> one memset zeroes both.
    (void)hipMemsetAsync(flags, 0, (size_t)((char*)row_start - (char*)flags), stream);
    k_detect <<<64, 256, 0, stream>>>((const unsigned char*)msk, idx, flags);
    k_hist   <<<gE, B, 0, stream>>>(ea, msk, idx, flags, cnt, rank);
    k_scanx  <<<NPART, 256, 0, stream>>>(cnt, gTotal, row_start);
    k_fill   <<<gE, B, 0, stream>>>(ea, msk, idx, flags, row_start, rank, csr);
    k_degconv<<<gG, B, 0, stream>>>(row_start, cnt, csr, (const float4*)x,
                                    t0, dinv, sd);

    k_gather_mid <<<gG, B, 0, stream>>>(row_start, cnt, csr, dinv, t0, tA);
    k_gather_mid <<<gG, B, 0, stream>>>(row_start, cnt, csr, dinv, tA, tB);
    k_gather_last<<<gG, B, 0, stream>>>(row_start, cnt, csr, dinv, sd,
                                        (const float4*)x, tA, tB, (float4*)out);
}